// Round 5
// baseline (11786.305 us; speedup 1.0000x reference)
//
#include <hip/hip_runtime.h>
#include <math.h>

// Problem constants
#define SEQ 2048
#define EMB_D 512
#define HID 512
#define NTAGS 12
#define START_TAG 10
#define STOP_TAG 11
#define NEGV (-10000.0f)
#define POISON 0xAAAAAAAAu

__device__ __forceinline__ float sigf(float x) { return 1.0f / (1.0f + expf(-x)); }

// sc0 (L1-bypass, XCD-L2 coherent) 8B load + drain. vmcnt(0) also drains any
// other in-flight VMEM, which is correct (just conservative).
__device__ __forceinline__ unsigned long long ld_sc0_u64(const float* p) {
    unsigned long long ap = (unsigned long long)p;
    unsigned long long v;
    asm volatile("global_load_dwordx2 %0, %1, off sc0\n\ts_waitcnt vmcnt(0)"
                 : "=v"(v)
                 : "v"(ap));
    return v;
}
// sc0 4B store: write-through L1 into the local XCD L2 (fast same-XCD path).
__device__ __forceinline__ void st_sc0_f32(float* p, float x) {
    unsigned long long ap = (unsigned long long)p;
    asm volatile("global_store_dword %0, %1, off sc0" ::"v"(ap), "v"(x));
}

// ---------------------------------------------------------------------------
// K0: embedding gather  x0[t][e] = emb[sentence[t]][e]
// ---------------------------------------------------------------------------
__global__ void k_embed(const int* __restrict__ sent, const float* __restrict__ emb,
                        float* __restrict__ x0) {
    int t = blockIdx.x;
    int tid = threadIdx.x;  // 128 threads, 128 float4 = 512 floats
    int row = sent[t];
    const float4* src = (const float4*)(emb + (size_t)row * EMB_D);
    float4* dst = (float4*)(x0 + (size_t)t * EMB_D);
    dst[tid] = src[tid];
}

// ---------------------------------------------------------------------------
// K1/K3: fp32 GEMM  C[d][m][n] = sum_k A[m][k] * B[d][n][k] + biasA[d][n]+biasB[d][n]
// A[m][k] = (k<512 ? Af[m*512+k] : Ab[m*512+(k-512)])  (handles concat input)
// M = N = 2048, K in {512,1024}. 128x128 tile, BK=16, 256 threads, 8x8/thread.
// Accumulation strictly k-ascending per output -> bit-identical to ref.
// ---------------------------------------------------------------------------
#define GBM 128
#define GBN 128
#define GBK 16
#define GLD 132

__global__ __launch_bounds__(256) void k_gemm(
    const float* __restrict__ Af, const float* __restrict__ Ab,
    const float* __restrict__ B,
    const float* __restrict__ biasA, const float* __restrict__ biasB,
    float* __restrict__ C, int K) {
    const int N = 2048;
    int dir = blockIdx.z;
    const float* Bd = B + (size_t)dir * N * K;
    const float* bA = biasA + dir * N;
    const float* bB = biasB + dir * N;
    float* Cd = C + (size_t)dir * 2048 * N;
    int m0 = blockIdx.y * GBM, n0 = blockIdx.x * GBN;

    __shared__ float As[GBK * GLD];
    __shared__ float Bs[GBK * GLD];

    int tid = threadIdx.x;
    int lrow = tid >> 1;        // 0..127
    int lk = (tid & 1) * 8;     // 0 or 8
    int tx = tid & 15, ty = tid >> 4;

    float acc[8][8] = {};

    for (int kt = 0; kt < K; kt += GBK) {
        {
            int m = m0 + lrow;
            const float* base = (kt < 512) ? (Af + (size_t)m * 512 + kt)
                                           : (Ab + (size_t)m * 512 + (kt - 512));
            float4 v0 = *(const float4*)(base + lk);
            float4 v1 = *(const float4*)(base + lk + 4);
            As[(lk + 0) * GLD + lrow] = v0.x;
            As[(lk + 1) * GLD + lrow] = v0.y;
            As[(lk + 2) * GLD + lrow] = v0.z;
            As[(lk + 3) * GLD + lrow] = v0.w;
            As[(lk + 4) * GLD + lrow] = v1.x;
            As[(lk + 5) * GLD + lrow] = v1.y;
            As[(lk + 6) * GLD + lrow] = v1.z;
            As[(lk + 7) * GLD + lrow] = v1.w;
        }
        {
            int n = n0 + lrow;
            const float* base = Bd + (size_t)n * K + kt;
            float4 v0 = *(const float4*)(base + lk);
            float4 v1 = *(const float4*)(base + lk + 4);
            Bs[(lk + 0) * GLD + lrow] = v0.x;
            Bs[(lk + 1) * GLD + lrow] = v0.y;
            Bs[(lk + 2) * GLD + lrow] = v0.z;
            Bs[(lk + 3) * GLD + lrow] = v0.w;
            Bs[(lk + 4) * GLD + lrow] = v1.x;
            Bs[(lk + 5) * GLD + lrow] = v1.y;
            Bs[(lk + 6) * GLD + lrow] = v1.z;
            Bs[(lk + 7) * GLD + lrow] = v1.w;
        }
        __syncthreads();
#pragma unroll
        for (int kk = 0; kk < GBK; ++kk) {
            float4 a0 = *(const float4*)&As[kk * GLD + ty * 8];
            float4 a1 = *(const float4*)&As[kk * GLD + ty * 8 + 4];
            float4 b0 = *(const float4*)&Bs[kk * GLD + tx * 8];
            float4 b1 = *(const float4*)&Bs[kk * GLD + tx * 8 + 4];
            float av[8] = {a0.x, a0.y, a0.z, a0.w, a1.x, a1.y, a1.z, a1.w};
            float bv[8] = {b0.x, b0.y, b0.z, b0.w, b1.x, b1.y, b1.z, b1.w};
#pragma unroll
            for (int i = 0; i < 8; ++i)
#pragma unroll
                for (int j = 0; j < 8; ++j) acc[i][j] += av[i] * bv[j];
        }
        __syncthreads();
    }
#pragma unroll
    for (int i = 0; i < 8; ++i) {
        int m = m0 + ty * 8 + i;
#pragma unroll
        for (int j = 0; j < 8; ++j) {
            int n = n0 + tx * 8 + j;
            Cd[(size_t)m * N + n] = acc[i][j] + bA[n] + bB[n];
        }
    }
}

// ---------------------------------------------------------------------------
// K2/K4: LSTM recurrence, one layer, both directions.
// R5: XCD-local communication.
//  - Launch 256 WGs; only bid%8==0 (-> XCD0 under the round-robin dispatch
//    mapping) runs direction 0, bid%8==1 (-> XCD1) runs direction 1; the
//    other 192 exit. All 32 WGs of a direction then share ONE XCD L2, so
//    cross-WG h traffic can ride sc0 (L1-bypass, L2-coherent) ops at ~200cy
//    RTT instead of agent-scope (MALL) ~600-900cy.
//  - Correctness does NOT depend on the mapping: producers dual-store
//    (sc0 fast path + the proven agent-scope atomic store), consumers try a
//    few sc0 polls then fall into an alternating agent/sc0 loop. Locations
//    are write-once, so stale reads can only return poison -> retry.
//  - Own-WG short-circuit: wave0 writes its own 16 units' h directly into
//    next iteration's LDS staging; the 8 threads whose pair is WG-local
//    never poll global at all.
//  - No FP change anywhere: dot split, activation placement, gate order all
//    identical to R1/R4 -> bit-identical outputs.
// ---------------------------------------------------------------------------
#define HPAD 132   // padded section stride (floats); 132 mod 32 = 4 banks

__global__ __launch_bounds__(256, 1) void k_lstm(
    const float* __restrict__ Whh,  // [2][2048][512]
    const float* __restrict__ Gi,   // [2][2048][2048]  (Wih@x + bih + bhh)
    float* __restrict__ hstore)     // [2][2048][512], pre-poisoned 0xAA
{
    int bid = blockIdx.x;
    int xsel = bid & 7;
    if (xsel >= 2) return;          // only XCD0/XCD1 groups participate
    int dir = xsel;
    int slice = bid >> 3;           // 0..31
    int u_base = slice * 16;
    int tid = threadIdx.x;

    const float* Whh_d = Whh + (size_t)dir * 2048 * 512;
    const float* Gi_d = Gi + (size_t)dir * 2048 * 2048;
    float* h_d = hstore + (size_t)dir * 2048 * 512;

    int rl = tid >> 2;   // local gate row 0..63
    int kp = tid & 3;    // k-quarter
    int gg = rl >> 4;    // gate (i,f,g,o)
    int uu = rl & 15;    // unit offset 0..15
    int r = gg * 512 + u_base + uu;  // global gate-row in [0,2048)

    // weights: w[j] = Whh[dir][r][kp*128 + j]
    float w[128];
    {
        const float* wsrc = Whh_d + (size_t)r * 512 + kp * 128;
#pragma unroll
        for (int j = 0; j < 128; j += 4) {
            float4 v = *(const float4*)(wsrc + j);
            w[j] = v.x; w[j + 1] = v.y; w[j + 2] = v.z; w[j + 3] = v.w;
        }
    }

    __shared__ __align__(16) float hlds[4 * HPAD];  // 4 padded k-sections
    __shared__ float gdot[64];
    float c_reg = 0.0f;

    // staging position for this thread's h pair (values 2*tid, 2*tid+1):
    int sec = tid >> 6;
    int soff = (tid & 63) * 2;
    float* hstage = hlds + sec * HPAD + soff;
    // is this thread's pair produced by this WG? (units u_base..u_base+15)
    bool own_pair = (tid >= slice * 8) && (tid < slice * 8 + 8);

    // prologue: Gi for the first step (kp==0 lanes only)
    float gi = 0.f;
    {
        int t0 = dir ? 2047 : 0;
        if (kp == 0) gi = Gi_d[(size_t)t0 * 2048 + r];
    }

    for (int it = 0; it < 2048; ++it) {
        int t = dir ? (2047 - it) : it;

        if (it == 0) {
            hstage[0] = 0.f;
            hstage[1] = 0.f;
        } else if (!own_pair) {
            int tprev = dir ? (t + 1) : (t - 1);
            const float* srcf = h_d + (size_t)tprev * 512 + 2 * tid;
            unsigned long long v;
            // fast path: spin the XCD-local L2
            int tries = 0;
            for (;;) {
                v = ld_sc0_u64(srcf);
                if ((unsigned)v != POISON && (unsigned)(v >> 32) != POISON) break;
                if (++tries >= 6) {
                    // fallback: alternate agent (MALL, correctness anchor) and
                    // sc0 (fast if producer is actually XCD-local) samples.
                    const unsigned long long* src = (const unsigned long long*)srcf;
                    for (;;) {
                        v = __hip_atomic_load(src, __ATOMIC_RELAXED,
                                              __HIP_MEMORY_SCOPE_AGENT);
                        if ((unsigned)v != POISON && (unsigned)(v >> 32) != POISON)
                            break;
                        v = ld_sc0_u64(srcf);
                        if ((unsigned)v != POISON && (unsigned)(v >> 32) != POISON)
                            break;
                    }
                    break;
                }
            }
            hstage[0] = __uint_as_float((unsigned)v);
            hstage[1] = __uint_as_float((unsigned)(v >> 32));
        }
        // own_pair threads: wave0 wrote their slots at the end of last iter.
        __syncthreads();

        // prefetch NEXT step's Gi (off the critical path)
        float gi_next = 0.f;
        if (kp == 0 && it + 1 < 2048) {
            int tn = dir ? (t - 1) : (t + 1);
            gi_next = Gi_d[(size_t)tn * 2048 + r];
        }

        // partial dot over this thread's k-quarter (conflict-free padded reads)
        float p = 0.f;
        const float4* h4 = (const float4*)(hlds + kp * HPAD);
#pragma unroll
        for (int j4 = 0; j4 < 32; ++j4) {
            float4 hv = h4[j4];
            p += w[4 * j4 + 0] * hv.x;
            p += w[4 * j4 + 1] * hv.y;
            p += w[4 * j4 + 2] * hv.z;
            p += w[4 * j4 + 3] * hv.w;
        }
        p += __shfl_xor(p, 1);
        p += __shfl_xor(p, 2);
        if (kp == 0) {
            float v = p + gi;
            gdot[rl] = (gg == 2) ? tanhf(v) : sigf(v);
        }
        __syncthreads();

        if (tid < 16) {
            float iv = gdot[0 * 16 + tid];  // sig(i)
            float fv = gdot[1 * 16 + tid];  // sig(f)
            float gv = gdot[2 * 16 + tid];  // tanh(g)
            float ov = gdot[3 * 16 + tid];  // sig(o)
            float c = fv * c_reg + iv * gv;
            float h = ov * tanhf(c);
            c_reg = c;
            int g = u_base + tid;
            // own-unit short-circuit: stage directly for next iteration
            hlds[(g >> 7) * HPAD + (g & 127)] = h;
            // fast path for same-XCD consumers: sc0 write into local L2
            st_sc0_f32(h_d + (size_t)t * 512 + g, h);
            // correctness anchor: agent-scope store to the coherent point
            __hip_atomic_store(h_d + (size_t)t * 512 + g, h,
                               __ATOMIC_RELAXED, __HIP_MEMORY_SCOPE_AGENT);
        }
        gi = gi_next;
        // no trailing barrier: next iteration's hlds writes (staging + wave0
        // own-unit writes) are separated from this iteration's reads by the
        // two barriers above / the poll gating.
    }
}

// ---------------------------------------------------------------------------
// K5: feats[t][tag] = sum_k concat(h1f[t],h1b[t])[k] * W_tag[tag][k] + b_tag[tag]
// one 64-thread block per t
// ---------------------------------------------------------------------------
__global__ __launch_bounds__(64) void k_feats(
    const float* __restrict__ h1,  // [2][2048][512]
    const float* __restrict__ Wt,  // [12][1024]
    const float* __restrict__ bt,  // [12]
    float* __restrict__ feats)     // [2048][12]
{
    int t = blockIdx.x;
    int lane = threadIdx.x;
    __shared__ __align__(16) float xl[1024];
    const float4* hf = (const float4*)(h1 + (size_t)t * 512);
    const float4* hb = (const float4*)(h1 + (size_t)(2048 + t) * 512);
    ((float4*)xl)[lane] = hf[lane];
    ((float4*)xl)[lane + 64] = hf[lane + 64];
    ((float4*)xl)[128 + lane] = hb[lane];
    ((float4*)xl)[128 + lane + 64] = hb[lane + 64];
    __syncthreads();
    for (int tag = 0; tag < NTAGS; ++tag) {
        const float* wrow = Wt + tag * 1024;
        float s = 0.f;
        for (int k = lane; k < 1024; k += 64) s += xl[k] * wrow[k];
#pragma unroll
        for (int off = 32; off; off >>= 1) s += __shfl_xor(s, off);
        if (lane == 0) feats[t * NTAGS + tag] = s + bt[tag];
    }
}

// ---------------------------------------------------------------------------
// K6: Viterbi forward + backtrack, single 64-thread block.
// ---------------------------------------------------------------------------
__global__ __launch_bounds__(64) void k_viterbi(
    const float* __restrict__ feats, const float* __restrict__ trans,
    float* __restrict__ out) {
    __shared__ float fv[2][NTAGS];
    __shared__ unsigned char bp[SEQ * NTAGS];  // 24 KB
    __shared__ float featbuf[256 * NTAGS];     // 12 KB
    __shared__ float term[NTAGS];
    int lane = threadIdx.x;

    float tr[NTAGS];
    if (lane < NTAGS) {
#pragma unroll
        for (int p = 0; p < NTAGS; ++p) tr[p] = trans[lane * NTAGS + p];
        fv[0][lane] = (lane == START_TAG) ? 0.f : NEGV;
    }
    __syncthreads();

    int cur = 0;
    for (int tc = 0; tc < SEQ; tc += 256) {
        for (int i = lane; i < 256 * NTAGS; i += 64) featbuf[i] = feats[tc * NTAGS + i];
        __syncthreads();
        for (int tt = 0; tt < 256; ++tt) {
            int t = tc + tt;
            if (lane < NTAGS) {
                float best = fv[cur][0] + tr[0];
                int bi = 0;
#pragma unroll
                for (int p = 1; p < NTAGS; ++p) {
                    float s = fv[cur][p] + tr[p];
                    if (s > best) { best = s; bi = p; }  // strict > keeps first max (jnp.argmax)
                }
                bp[t * NTAGS + lane] = (unsigned char)bi;
                fv[cur ^ 1][lane] = best + featbuf[tt * NTAGS + lane];
            }
            cur ^= 1;
            __syncthreads();
        }
    }

    if (lane < NTAGS) term[lane] = fv[cur][lane] + trans[STOP_TAG * NTAGS + lane];
    __syncthreads();
    if (lane == 0) {
        float best = term[0];
        int bi = 0;
        for (int p = 1; p < NTAGS; ++p) {
            if (term[p] > best) { best = term[p]; bi = p; }
        }
        out[0] = best;
        int tag = bi;
        out[1 + (SEQ - 1)] = (float)tag;
        for (int t = SEQ - 1; t >= 1; --t) {
            tag = bp[t * NTAGS + tag];
            out[t] = (float)tag;  // out[1+(t-1)]
        }
    }
}

// ---------------------------------------------------------------------------
extern "C" void kernel_launch(void* const* d_in, const int* in_sizes, int n_in,
                              void* d_out, int out_size, void* d_ws, size_t ws_size,
                              hipStream_t stream) {
    const int* sent = (const int*)d_in[0];
    const float* emb = (const float*)d_in[1];
    const float* Wih0 = (const float*)d_in[2];
    const float* Whh0 = (const float*)d_in[3];
    const float* bih0 = (const float*)d_in[4];
    const float* bhh0 = (const float*)d_in[5];
    const float* Wih1 = (const float*)d_in[6];
    const float* Whh1 = (const float*)d_in[7];
    const float* bih1 = (const float*)d_in[8];
    const float* bhh1 = (const float*)d_in[9];
    const float* Wtag = (const float*)d_in[10];
    const float* btag = (const float*)d_in[11];
    const float* trans = (const float*)d_in[12];
    float* out = (float*)d_out;

    char* ws = (char*)d_ws;
    size_t off = 0;
    auto alloc = [&](size_t bytes) {
        void* p = ws + off;
        off += (bytes + 255) & ~(size_t)255;
        return p;
    };
    float* x0 = (float*)alloc(2048ull * 512 * 4);          // 4 MB
    float* Gi = (float*)alloc(2ull * 2048 * 2048 * 4);     // 32 MB (reused layer0/1)
    float* h0 = (float*)alloc(2ull * 2048 * 512 * 4);      // 8 MB
    float* h1 = (float*)alloc(2ull * 2048 * 512 * 4);      // 8 MB
    float* feats = (float*)alloc(2048ull * NTAGS * 4);

    // poison h buffers: "not yet written" sentinel for the data-polling sync
    hipMemsetAsync(h0, 0xAA, 2ull * 2048 * 512 * 4, stream);
    hipMemsetAsync(h1, 0xAA, 2ull * 2048 * 512 * 4, stream);

    k_embed<<<2048, 128, 0, stream>>>(sent, emb, x0);

    dim3 gg(16, 16, 2);
    // layer 0 input gates: Gi = x0 @ Wih0^T + bih0 + bhh0  (K=512)
    k_gemm<<<gg, 256, 0, stream>>>(x0, x0, Wih0, bih0, bhh0, Gi, 512);
    // layer 0 recurrence (256 WGs; 64 participate, XCD-selected by bid%8)
    k_lstm<<<256, 256, 0, stream>>>(Whh0, Gi, h0);
    // layer 1 input gates: Gi = concat(h0f,h0b) @ Wih1^T + b  (K=1024)
    k_gemm<<<gg, 256, 0, stream>>>(h0, h0 + 2048ull * 512, Wih1, bih1, bhh1, Gi, 1024);
    // layer 1 recurrence
    k_lstm<<<256, 256, 0, stream>>>(Whh1, Gi, h1);
    // tag projection
    k_feats<<<2048, 64, 0, stream>>>(h1, Wtag, btag, feats);
    // viterbi decode
    k_viterbi<<<1, 64, 0, stream>>>(feats, trans, out);
}

// Round 6
// 11066.948 us; speedup vs baseline: 1.0650x; 1.0650x over previous
//
#include <hip/hip_runtime.h>
#include <math.h>

// Problem constants
#define SEQ 2048
#define EMB_D 512
#define HID 512
#define NTAGS 12
#define START_TAG 10
#define STOP_TAG 11
#define NEGV (-10000.0f)
#define POISON 0xAAAAAAAAu

__device__ __forceinline__ float sigf(float x) { return 1.0f / (1.0f + expf(-x)); }

// ---------------------------------------------------------------------------
// K0: embedding gather  x0[t][e] = emb[sentence[t]][e]
// ---------------------------------------------------------------------------
__global__ void k_embed(const int* __restrict__ sent, const float* __restrict__ emb,
                        float* __restrict__ x0) {
    int t = blockIdx.x;
    int tid = threadIdx.x;  // 128 threads, 128 float4 = 512 floats
    int row = sent[t];
    const float4* src = (const float4*)(emb + (size_t)row * EMB_D);
    float4* dst = (float4*)(x0 + (size_t)t * EMB_D);
    dst[tid] = src[tid];
}

// ---------------------------------------------------------------------------
// K1/K3: fp32 GEMM  C[d][m][n] = sum_k A[m][k] * B[d][n][k] + biasA[d][n]+biasB[d][n]
// A[m][k] = (k<512 ? Af[m*512+k] : Ab[m*512+(k-512)])  (handles concat input)
// M = N = 2048, K in {512,1024}. 128x128 tile, BK=16, 256 threads, 8x8/thread.
// Accumulation strictly k-ascending per output -> bit-identical to ref.
// ---------------------------------------------------------------------------
#define GBM 128
#define GBN 128
#define GBK 16
#define GLD 132

__global__ __launch_bounds__(256) void k_gemm(
    const float* __restrict__ Af, const float* __restrict__ Ab,
    const float* __restrict__ B,
    const float* __restrict__ biasA, const float* __restrict__ biasB,
    float* __restrict__ C, int K) {
    const int N = 2048;
    int dir = blockIdx.z;
    const float* Bd = B + (size_t)dir * N * K;
    const float* bA = biasA + dir * N;
    const float* bB = biasB + dir * N;
    float* Cd = C + (size_t)dir * 2048 * N;
    int m0 = blockIdx.y * GBM, n0 = blockIdx.x * GBN;

    __shared__ float As[GBK * GLD];
    __shared__ float Bs[GBK * GLD];

    int tid = threadIdx.x;
    int lrow = tid >> 1;        // 0..127
    int lk = (tid & 1) * 8;     // 0 or 8
    int tx = tid & 15, ty = tid >> 4;

    float acc[8][8] = {};

    for (int kt = 0; kt < K; kt += GBK) {
        {
            int m = m0 + lrow;
            const float* base = (kt < 512) ? (Af + (size_t)m * 512 + kt)
                                           : (Ab + (size_t)m * 512 + (kt - 512));
            float4 v0 = *(const float4*)(base + lk);
            float4 v1 = *(const float4*)(base + lk + 4);
            As[(lk + 0) * GLD + lrow] = v0.x;
            As[(lk + 1) * GLD + lrow] = v0.y;
            As[(lk + 2) * GLD + lrow] = v0.z;
            As[(lk + 3) * GLD + lrow] = v0.w;
            As[(lk + 4) * GLD + lrow] = v1.x;
            As[(lk + 5) * GLD + lrow] = v1.y;
            As[(lk + 6) * GLD + lrow] = v1.z;
            As[(lk + 7) * GLD + lrow] = v1.w;
        }
        {
            int n = n0 + lrow;
            const float* base = Bd + (size_t)n * K + kt;
            float4 v0 = *(const float4*)(base + lk);
            float4 v1 = *(const float4*)(base + lk + 4);
            Bs[(lk + 0) * GLD + lrow] = v0.x;
            Bs[(lk + 1) * GLD + lrow] = v0.y;
            Bs[(lk + 2) * GLD + lrow] = v0.z;
            Bs[(lk + 3) * GLD + lrow] = v0.w;
            Bs[(lk + 4) * GLD + lrow] = v1.x;
            Bs[(lk + 5) * GLD + lrow] = v1.y;
            Bs[(lk + 6) * GLD + lrow] = v1.z;
            Bs[(lk + 7) * GLD + lrow] = v1.w;
        }
        __syncthreads();
#pragma unroll
        for (int kk = 0; kk < GBK; ++kk) {
            float4 a0 = *(const float4*)&As[kk * GLD + ty * 8];
            float4 a1 = *(const float4*)&As[kk * GLD + ty * 8 + 4];
            float4 b0 = *(const float4*)&Bs[kk * GLD + tx * 8];
            float4 b1 = *(const float4*)&Bs[kk * GLD + tx * 8 + 4];
            float av[8] = {a0.x, a0.y, a0.z, a0.w, a1.x, a1.y, a1.z, a1.w};
            float bv[8] = {b0.x, b0.y, b0.z, b0.w, b1.x, b1.y, b1.z, b1.w};
#pragma unroll
            for (int i = 0; i < 8; ++i)
#pragma unroll
                for (int j = 0; j < 8; ++j) acc[i][j] += av[i] * bv[j];
        }
        __syncthreads();
    }
#pragma unroll
    for (int i = 0; i < 8; ++i) {
        int m = m0 + ty * 8 + i;
#pragma unroll
        for (int j = 0; j < 8; ++j) {
            int n = n0 + tx * 8 + j;
            Cd[(size_t)m * N + n] = acc[i][j] + bA[n] + bB[n];
        }
    }
}

// ---------------------------------------------------------------------------
// K2/K4: LSTM recurrence, one layer, both directions.  (R4 structure)
// 64 WGs (32 per direction), 256 threads each, persistent over 2048 steps.
// Each WG owns 16 hidden units (64 gate rows).
// Cross-WG h broadcast: relaxed agent-scope atomic stores; consumers poll
// the data words themselves (0xAA poison = "not yet written").
//
// R6 = R4 + ONE change: Whh weights pinned in AGPRs.
//   VGPR_Count=84-88 across R0-R5 proves w[128] was never register-resident:
//   the compiler rematerializes the weight loads inside the step loop,
//   streaming 128KB/CU/step from L2 (~2000cy/step, the dominant term —
//   confirmed by R5: concentrating 32 WGs on one XCD's L2 regressed 38%).
//   R3's VGPR pin spilled to scratch; AGPRs (unified 512-reg file on gfx950)
//   have separate class pressure and no cheap spill path:
//     - write once:  v_accvgpr_write_b32 ("=a")
//     - read per use: volatile v_accvgpr_read_b32 ("=v") — volatile stops
//       LICM from hoisting 128 reads (which would recreate the VGPR spill).
//   Arithmetic sequence is unchanged -> bit-identical results.
// ---------------------------------------------------------------------------
#define HPAD 132   // padded section stride (floats); 132 mod 32 = 4 banks

__global__ __launch_bounds__(256, 1) void k_lstm(
    const float* __restrict__ Whh,  // [2][2048][512]
    const float* __restrict__ Gi,   // [2][2048][2048]  (Wih@x + bih + bhh)
    float* __restrict__ hstore)     // [2][2048][512], pre-poisoned 0xAA
{
    int wg = blockIdx.x;
    int dir = wg >> 5;
    int slice = wg & 31;
    int u_base = slice * 16;
    int tid = threadIdx.x;

    const float* Whh_d = Whh + (size_t)dir * 2048 * 512;
    const float* Gi_d = Gi + (size_t)dir * 2048 * 2048;
    float* h_d = hstore + (size_t)dir * 2048 * 512;

    int rl = tid >> 2;   // local gate row 0..63
    int kp = tid & 3;    // k-quarter
    int gg = rl >> 4;    // gate (i,f,g,o)
    int uu = rl & 15;    // unit offset 0..15
    int r = gg * 512 + u_base + uu;  // global gate-row in [0,2048)
    // (gg,uu) mapping makes kp==0 lanes' Gi addresses consecutive per gate.

    // load weights, then pin into AGPRs: wa[j] = Whh[dir][r][kp*128 + j]
    float wa[128];
    {
        float w[128];
        const float* wsrc = Whh_d + (size_t)r * 512 + kp * 128;
#pragma unroll
        for (int j = 0; j < 128; j += 4) {
            float4 v = *(const float4*)(wsrc + j);
            w[j] = v.x; w[j + 1] = v.y; w[j + 2] = v.z; w[j + 3] = v.w;
        }
#pragma unroll
        for (int j = 0; j < 128; ++j)
            asm volatile("v_accvgpr_write_b32 %0, %1" : "=a"(wa[j]) : "v"(w[j]));
    }

    __shared__ __align__(16) float hlds[4 * HPAD];  // 4 padded k-sections
    __shared__ float gdot[64];
    float c_reg = 0.0f;

    // staging position for this thread's h pair (values 2*tid, 2*tid+1):
    int sec = tid >> 6;            // which 128-float section
    int soff = (tid & 63) * 2;     // offset within section (even, 8B aligned)
    float* hstage = hlds + sec * HPAD + soff;

    // prologue: Gi for the first step (kp==0 lanes only)
    float gi = 0.f;
    {
        int t0 = dir ? 2047 : 0;
        if (kp == 0) gi = Gi_d[(size_t)t0 * 2048 + r];
    }

    for (int it = 0; it < 2048; ++it) {
        int t = dir ? (2047 - it) : it;

        if (it == 0) {
            hstage[0] = 0.f;
            hstage[1] = 0.f;
        } else {
            int tprev = dir ? (t + 1) : (t - 1);
            const unsigned long long* src =
                (const unsigned long long*)(h_d + (size_t)tprev * 512) + tid;
            unsigned long long v;
            do {
                v = __hip_atomic_load(src, __ATOMIC_RELAXED, __HIP_MEMORY_SCOPE_AGENT);
            } while ((unsigned)v == POISON || (unsigned)(v >> 32) == POISON);
            hstage[0] = __uint_as_float((unsigned)v);
            hstage[1] = __uint_as_float((unsigned)(v >> 32));
        }
        __syncthreads();

        // prefetch NEXT step's Gi (off the critical path)
        float gi_next = 0.f;
        if (kp == 0 && it + 1 < 2048) {
            int tn = dir ? (t - 1) : (t + 1);
            gi_next = Gi_d[(size_t)tn * 2048 + r];
        }

        // partial dot over this thread's k-quarter; weights come from AGPRs
        // (two v_accvgpr_read per FMA pair instead of an L2 re-stream).
        float p = 0.f;
        const float4* h4 = (const float4*)(hlds + kp * HPAD);
#pragma unroll
        for (int j4 = 0; j4 < 32; ++j4) {
            float4 hv = h4[j4];
            float a0, a1, a2, a3;
            asm volatile("v_accvgpr_read_b32 %0, %1" : "=v"(a0) : "a"(wa[4 * j4 + 0]));
            asm volatile("v_accvgpr_read_b32 %0, %1" : "=v"(a1) : "a"(wa[4 * j4 + 1]));
            asm volatile("v_accvgpr_read_b32 %0, %1" : "=v"(a2) : "a"(wa[4 * j4 + 2]));
            asm volatile("v_accvgpr_read_b32 %0, %1" : "=v"(a3) : "a"(wa[4 * j4 + 3]));
            p += a0 * hv.x;
            p += a1 * hv.y;
            p += a2 * hv.z;
            p += a3 * hv.w;
        }
        p += __shfl_xor(p, 1);
        p += __shfl_xor(p, 2);
        if (kp == 0) {
            float v = p + gi;
            // activation applied here: 64 gate rows in parallel across waves.
            gdot[rl] = (gg == 2) ? tanhf(v) : sigf(v);
        }
        __syncthreads();

        if (tid < 16) {
            float iv = gdot[0 * 16 + tid];  // sig(i)
            float fv = gdot[1 * 16 + tid];  // sig(f)
            float gv = gdot[2 * 16 + tid];  // tanh(g)
            float ov = gdot[3 * 16 + tid];  // sig(o)
            float c = fv * c_reg + iv * gv;
            float h = ov * tanhf(c);
            c_reg = c;
            // publish at the coherent point; the value itself is the flag.
            // 16 consecutive 4B stores from one wave -> one 64B line write.
            __hip_atomic_store(h_d + (size_t)t * 512 + u_base + tid, h,
                               __ATOMIC_RELAXED, __HIP_MEMORY_SCOPE_AGENT);
        }
        gi = gi_next;
        // no trailing barrier needed: next iteration's hlds/gdot writes are
        // separated from this iteration's reads by the two barriers above.
    }
}

// ---------------------------------------------------------------------------
// K5: feats[t][tag] = sum_k concat(h1f[t],h1b[t])[k] * W_tag[tag][k] + b_tag[tag]
// one 64-thread block per t
// ---------------------------------------------------------------------------
__global__ __launch_bounds__(64) void k_feats(
    const float* __restrict__ h1,  // [2][2048][512]
    const float* __restrict__ Wt,  // [12][1024]
    const float* __restrict__ bt,  // [12]
    float* __restrict__ feats)     // [2048][12]
{
    int t = blockIdx.x;
    int lane = threadIdx.x;
    __shared__ __align__(16) float xl[1024];
    const float4* hf = (const float4*)(h1 + (size_t)t * 512);
    const float4* hb = (const float4*)(h1 + (size_t)(2048 + t) * 512);
    ((float4*)xl)[lane] = hf[lane];
    ((float4*)xl)[lane + 64] = hf[lane + 64];
    ((float4*)xl)[128 + lane] = hb[lane];
    ((float4*)xl)[128 + lane + 64] = hb[lane + 64];
    __syncthreads();
    for (int tag = 0; tag < NTAGS; ++tag) {
        const float* wrow = Wt + tag * 1024;
        float s = 0.f;
        for (int k = lane; k < 1024; k += 64) s += xl[k] * wrow[k];
#pragma unroll
        for (int off = 32; off; off >>= 1) s += __shfl_xor(s, off);
        if (lane == 0) feats[t * NTAGS + tag] = s + bt[tag];
    }
}

// ---------------------------------------------------------------------------
// K6: Viterbi forward + backtrack, single 64-thread block.
// ---------------------------------------------------------------------------
__global__ __launch_bounds__(64) void k_viterbi(
    const float* __restrict__ feats, const float* __restrict__ trans,
    float* __restrict__ out) {
    __shared__ float fv[2][NTAGS];
    __shared__ unsigned char bp[SEQ * NTAGS];  // 24 KB
    __shared__ float featbuf[256 * NTAGS];     // 12 KB
    __shared__ float term[NTAGS];
    int lane = threadIdx.x;

    float tr[NTAGS];
    if (lane < NTAGS) {
#pragma unroll
        for (int p = 0; p < NTAGS; ++p) tr[p] = trans[lane * NTAGS + p];
        fv[0][lane] = (lane == START_TAG) ? 0.f : NEGV;
    }
    __syncthreads();

    int cur = 0;
    for (int tc = 0; tc < SEQ; tc += 256) {
        for (int i = lane; i < 256 * NTAGS; i += 64) featbuf[i] = feats[tc * NTAGS + i];
        __syncthreads();
        for (int tt = 0; tt < 256; ++tt) {
            int t = tc + tt;
            if (lane < NTAGS) {
                float best = fv[cur][0] + tr[0];
                int bi = 0;
#pragma unroll
                for (int p = 1; p < NTAGS; ++p) {
                    float s = fv[cur][p] + tr[p];
                    if (s > best) { best = s; bi = p; }  // strict > keeps first max (jnp.argmax)
                }
                bp[t * NTAGS + lane] = (unsigned char)bi;
                fv[cur ^ 1][lane] = best + featbuf[tt * NTAGS + lane];
            }
            cur ^= 1;
            __syncthreads();
        }
    }

    if (lane < NTAGS) term[lane] = fv[cur][lane] + trans[STOP_TAG * NTAGS + lane];
    __syncthreads();
    if (lane == 0) {
        float best = term[0];
        int bi = 0;
        for (int p = 1; p < NTAGS; ++p) {
            if (term[p] > best) { best = term[p]; bi = p; }
        }
        out[0] = best;
        int tag = bi;
        out[1 + (SEQ - 1)] = (float)tag;
        for (int t = SEQ - 1; t >= 1; --t) {
            tag = bp[t * NTAGS + tag];
            out[t] = (float)tag;  // out[1+(t-1)]
        }
    }
}

// ---------------------------------------------------------------------------
extern "C" void kernel_launch(void* const* d_in, const int* in_sizes, int n_in,
                              void* d_out, int out_size, void* d_ws, size_t ws_size,
                              hipStream_t stream) {
    const int* sent = (const int*)d_in[0];
    const float* emb = (const float*)d_in[1];
    const float* Wih0 = (const float*)d_in[2];
    const float* Whh0 = (const float*)d_in[3];
    const float* bih0 = (const float*)d_in[4];
    const float* bhh0 = (const float*)d_in[5];
    const float* Wih1 = (const float*)d_in[6];
    const float* Whh1 = (const float*)d_in[7];
    const float* bih1 = (const float*)d_in[8];
    const float* bhh1 = (const float*)d_in[9];
    const float* Wtag = (const float*)d_in[10];
    const float* btag = (const float*)d_in[11];
    const float* trans = (const float*)d_in[12];
    float* out = (float*)d_out;

    char* ws = (char*)d_ws;
    size_t off = 0;
    auto alloc = [&](size_t bytes) {
        void* p = ws + off;
        off += (bytes + 255) & ~(size_t)255;
        return p;
    };
    float* x0 = (float*)alloc(2048ull * 512 * 4);          // 4 MB
    float* Gi = (float*)alloc(2ull * 2048 * 2048 * 4);     // 32 MB (reused layer0/1)
    float* h0 = (float*)alloc(2ull * 2048 * 512 * 4);      // 8 MB
    float* h1 = (float*)alloc(2ull * 2048 * 512 * 4);      // 8 MB
    float* feats = (float*)alloc(2048ull * NTAGS * 4);

    // poison h buffers: "not yet written" sentinel for the data-polling sync
    hipMemsetAsync(h0, 0xAA, 2ull * 2048 * 512 * 4, stream);
    hipMemsetAsync(h1, 0xAA, 2ull * 2048 * 512 * 4, stream);

    k_embed<<<2048, 128, 0, stream>>>(sent, emb, x0);

    dim3 gg(16, 16, 2);
    // layer 0 input gates: Gi = x0 @ Wih0^T + bih0 + bhh0  (K=512)
    k_gemm<<<gg, 256, 0, stream>>>(x0, x0, Wih0, bih0, bhh0, Gi, 512);
    // layer 0 recurrence
    k_lstm<<<64, 256, 0, stream>>>(Whh0, Gi, h0);
    // layer 1 input gates: Gi = concat(h0f,h0b) @ Wih1^T + b  (K=1024)
    k_gemm<<<gg, 256, 0, stream>>>(h0, h0 + 2048ull * 512, Wih1, bih1, bhh1, Gi, 1024);
    // layer 1 recurrence
    k_lstm<<<64, 256, 0, stream>>>(Whh1, Gi, h1);
    // tag projection
    k_feats<<<2048, 64, 0, stream>>>(h1, Wtag, btag, feats);
    // viterbi decode
    k_viterbi<<<1, 64, 0, stream>>>(feats, trans, out);
}

// Round 7
// 9027.862 us; speedup vs baseline: 1.3055x; 1.2259x over previous
//
#include <hip/hip_runtime.h>
#include <math.h>

// Problem constants
#define SEQ 2048
#define EMB_D 512
#define HID 512
#define NTAGS 12
#define START_TAG 10
#define STOP_TAG 11
#define NEGV (-10000.0f)
#define POISON 0xAAAAAAAAu

__device__ __forceinline__ float sigf(float x) { return 1.0f / (1.0f + expf(-x)); }

__device__ __forceinline__ unsigned long long ald64(const float* p) {
    return __hip_atomic_load((const unsigned long long*)p, __ATOMIC_RELAXED,
                             __HIP_MEMORY_SCOPE_AGENT);
}
__device__ __forceinline__ bool pois2(unsigned long long x) {
    return (unsigned)x == POISON || (unsigned)(x >> 32) == POISON;
}

// ---------------------------------------------------------------------------
// K0: embedding gather  x0[t][e] = emb[sentence[t]][e]
// ---------------------------------------------------------------------------
__global__ void k_embed(const int* __restrict__ sent, const float* __restrict__ emb,
                        float* __restrict__ x0) {
    int t = blockIdx.x;
    int tid = threadIdx.x;  // 128 threads, 128 float4 = 512 floats
    int row = sent[t];
    const float4* src = (const float4*)(emb + (size_t)row * EMB_D);
    float4* dst = (float4*)(x0 + (size_t)t * EMB_D);
    dst[tid] = src[tid];
}

// ---------------------------------------------------------------------------
// K1: fp32 GEMM (layer-0 input gates)  — 128x128 tile, BK=16, 8x8/thread.
// Accumulation strictly k-ascending per output -> bit-identical to ref.
// ---------------------------------------------------------------------------
#define GBM 128
#define GBN 128
#define GBK 16
#define GLD 132

__global__ __launch_bounds__(256) void k_gemm(
    const float* __restrict__ Af, const float* __restrict__ Ab,
    const float* __restrict__ B,
    const float* __restrict__ biasA, const float* __restrict__ biasB,
    float* __restrict__ C, int K) {
    const int N = 2048;
    int dir = blockIdx.z;
    const float* Bd = B + (size_t)dir * N * K;
    const float* bA = biasA + dir * N;
    const float* bB = biasB + dir * N;
    float* Cd = C + (size_t)dir * 2048 * N;
    int m0 = blockIdx.y * GBM, n0 = blockIdx.x * GBN;

    __shared__ float As[GBK * GLD];
    __shared__ float Bs[GBK * GLD];

    int tid = threadIdx.x;
    int lrow = tid >> 1;        // 0..127
    int lk = (tid & 1) * 8;     // 0 or 8
    int tx = tid & 15, ty = tid >> 4;

    float acc[8][8] = {};

    for (int kt = 0; kt < K; kt += GBK) {
        {
            int m = m0 + lrow;
            const float* base = (kt < 512) ? (Af + (size_t)m * 512 + kt)
                                           : (Ab + (size_t)m * 512 + (kt - 512));
            float4 v0 = *(const float4*)(base + lk);
            float4 v1 = *(const float4*)(base + lk + 4);
            As[(lk + 0) * GLD + lrow] = v0.x;
            As[(lk + 1) * GLD + lrow] = v0.y;
            As[(lk + 2) * GLD + lrow] = v0.z;
            As[(lk + 3) * GLD + lrow] = v0.w;
            As[(lk + 4) * GLD + lrow] = v1.x;
            As[(lk + 5) * GLD + lrow] = v1.y;
            As[(lk + 6) * GLD + lrow] = v1.z;
            As[(lk + 7) * GLD + lrow] = v1.w;
        }
        {
            int n = n0 + lrow;
            const float* base = Bd + (size_t)n * K + kt;
            float4 v0 = *(const float4*)(base + lk);
            float4 v1 = *(const float4*)(base + lk + 4);
            Bs[(lk + 0) * GLD + lrow] = v0.x;
            Bs[(lk + 1) * GLD + lrow] = v0.y;
            Bs[(lk + 2) * GLD + lrow] = v0.z;
            Bs[(lk + 3) * GLD + lrow] = v0.w;
            Bs[(lk + 4) * GLD + lrow] = v1.x;
            Bs[(lk + 5) * GLD + lrow] = v1.y;
            Bs[(lk + 6) * GLD + lrow] = v1.z;
            Bs[(lk + 7) * GLD + lrow] = v1.w;
        }
        __syncthreads();
#pragma unroll
        for (int kk = 0; kk < GBK; ++kk) {
            float4 a0 = *(const float4*)&As[kk * GLD + ty * 8];
            float4 a1 = *(const float4*)&As[kk * GLD + ty * 8 + 4];
            float4 b0 = *(const float4*)&Bs[kk * GLD + tx * 8];
            float4 b1 = *(const float4*)&Bs[kk * GLD + tx * 8 + 4];
            float av[8] = {a0.x, a0.y, a0.z, a0.w, a1.x, a1.y, a1.z, a1.w};
            float bv[8] = {b0.x, b0.y, b0.z, b0.w, b1.x, b1.y, b1.z, b1.w};
#pragma unroll
            for (int i = 0; i < 8; ++i)
#pragma unroll
                for (int j = 0; j < 8; ++j) acc[i][j] += av[i] * bv[j];
        }
        __syncthreads();
    }
#pragma unroll
    for (int i = 0; i < 8; ++i) {
        int m = m0 + ty * 8 + i;
#pragma unroll
        for (int j = 0; j < 8; ++j) {
            int n = n0 + tx * 8 + j;
            Cd[(size_t)m * N + n] = acc[i][j] + bA[n] + bB[n];
        }
    }
}

// ---------------------------------------------------------------------------
// LSTM recurrence body (R4-exact, proven 3905us/dispatch).
// 64 WGs (32/dir), 256 threads, persistent over 2048 steps; WG owns 16 units.
// Cross-WG h: relaxed agent-scope atomic stores; consumers poll the data
// words themselves (0xAA poison = "not yet written").
// ---------------------------------------------------------------------------
#define HPAD 132   // padded section stride (floats); 132 mod 32 = 4 banks

__device__ __forceinline__ void lstm_body(
    int wg,
    const float* __restrict__ Whh,  // [2][2048][512]
    const float* __restrict__ Gi,   // [2][2048][2048]
    float* __restrict__ hstore)     // [2][2048][512], pre-poisoned
{
    __shared__ __align__(16) float hlds[4 * HPAD];
    __shared__ float gdot[64];

    int dir = wg >> 5;
    int slice = wg & 31;
    int u_base = slice * 16;
    int tid = threadIdx.x;

    const float* Whh_d = Whh + (size_t)dir * 2048 * 512;
    const float* Gi_d = Gi + (size_t)dir * 2048 * 2048;
    float* h_d = hstore + (size_t)dir * 2048 * 512;

    int rl = tid >> 2;   // local gate row 0..63
    int kp = tid & 3;    // k-quarter
    int gg = rl >> 4;    // gate (i,f,g,o)
    int uu = rl & 15;    // unit offset 0..15
    int r = gg * 512 + u_base + uu;  // global gate-row in [0,2048)

    // weights: w[j] = Whh[dir][r][kp*128 + j]
    float w[128];
    {
        const float* wsrc = Whh_d + (size_t)r * 512 + kp * 128;
#pragma unroll
        for (int j = 0; j < 128; j += 4) {
            float4 v = *(const float4*)(wsrc + j);
            w[j] = v.x; w[j + 1] = v.y; w[j + 2] = v.z; w[j + 3] = v.w;
        }
    }

    float c_reg = 0.0f;

    int sec = tid >> 6;
    int soff = (tid & 63) * 2;
    float* hstage = hlds + sec * HPAD + soff;

    float gi = 0.f;
    {
        int t0 = dir ? 2047 : 0;
        if (kp == 0) gi = Gi_d[(size_t)t0 * 2048 + r];
    }

    for (int it = 0; it < 2048; ++it) {
        int t = dir ? (2047 - it) : it;

        if (it == 0) {
            hstage[0] = 0.f;
            hstage[1] = 0.f;
        } else {
            int tprev = dir ? (t + 1) : (t - 1);
            const unsigned long long* src =
                (const unsigned long long*)(h_d + (size_t)tprev * 512) + tid;
            unsigned long long v;
            do {
                v = __hip_atomic_load(src, __ATOMIC_RELAXED, __HIP_MEMORY_SCOPE_AGENT);
            } while ((unsigned)v == POISON || (unsigned)(v >> 32) == POISON);
            hstage[0] = __uint_as_float((unsigned)v);
            hstage[1] = __uint_as_float((unsigned)(v >> 32));
        }
        __syncthreads();

        // prefetch NEXT step's Gi (off the critical path)
        float gi_next = 0.f;
        if (kp == 0 && it + 1 < 2048) {
            int tn = dir ? (t - 1) : (t + 1);
            gi_next = Gi_d[(size_t)tn * 2048 + r];
        }

        float p = 0.f;
        const float4* h4 = (const float4*)(hlds + kp * HPAD);
#pragma unroll
        for (int j4 = 0; j4 < 32; ++j4) {
            float4 hv = h4[j4];
            p += w[4 * j4 + 0] * hv.x;
            p += w[4 * j4 + 1] * hv.y;
            p += w[4 * j4 + 2] * hv.z;
            p += w[4 * j4 + 3] * hv.w;
        }
        p += __shfl_xor(p, 1);
        p += __shfl_xor(p, 2);
        if (kp == 0) {
            float v = p + gi;
            gdot[rl] = (gg == 2) ? tanhf(v) : sigf(v);
        }
        __syncthreads();

        if (tid < 16) {
            float iv = gdot[0 * 16 + tid];  // sig(i)
            float fv = gdot[1 * 16 + tid];  // sig(f)
            float gv = gdot[2 * 16 + tid];  // tanh(g)
            float ov = gdot[3 * 16 + tid];  // sig(o)
            float c = fv * c_reg + iv * gv;
            float h = ov * tanhf(c);
            c_reg = c;
            __hip_atomic_store(h_d + (size_t)t * 512 + u_base + tid, h,
                               __ATOMIC_RELAXED, __HIP_MEMORY_SCOPE_AGENT);
        }
        gi = gi_next;
    }
}

__global__ __launch_bounds__(256, 1) void k_lstm(
    const float* __restrict__ Whh, const float* __restrict__ Gi,
    float* __restrict__ hstore) {
    lstm_body(blockIdx.x, Whh, Gi, hstore);
}

// ---------------------------------------------------------------------------
// GEMM-layer1 body (shadow work inside the lstm0 dispatch).
// Tile [tm,tn,dir] of Gi1 = concat(h0f,h0b) @ Wih1^T + bih1 + bhh1.
// Gating: waits for sentinel words of fwd row m0+127 (produced last by fwd)
// and bwd row m0 (produced last by bwd), sleep-throttled; then loads all A
// values via agent-scope atomic u64s with per-value poison-retry (per-XCD L2
// may hold stale poison; relaxed store visibility order is not guaranteed).
// Race-freedom on Gi reuse: this tile writes Gi[.][t'] only after loading the
// full non-poison h0 rows t', which were COMPUTED FROM Gi[.][t'] — the write
// is data-dependent on the layer-0 reads having completed.
// Accumulation order identical to k_gemm -> bit-identical results.
// ---------------------------------------------------------------------------
__device__ void gemm1_body(int bt, const float* h0, const float* Wih1,
                           const float* bih1, const float* bhh1, float* Gi) {
    __shared__ float As[GBK * GLD];
    __shared__ float Bs[GBK * GLD];
    __shared__ int ready;

    int dir = bt >> 8;
    int rem = bt & 255;
    int tm = rem >> 4, tn = rem & 15;
    int tid = threadIdx.x;

    const float* h0f = h0;
    const float* h0b = h0 + 2048ull * 512;
    const float* Bd = Wih1 + (size_t)dir * 2048 * 1024;
    const float* bA = bih1 + dir * 2048;
    const float* bB = bhh1 + dir * 2048;
    float* Cd = Gi + (size_t)dir * 2048 * 2048;
    int m0 = tm * GBM, n0 = tn * GBN;

    // --- readiness gate (throttled; one wave polls 64 sentinel words) ---
    if (tid == 0) ready = 0;
    __syncthreads();
    for (;;) {
        if (tid < 64) {
            int s = tid & 31;
            const float* base = (tid < 32) ? (h0f + (size_t)(m0 + 127) * 512)
                                           : (h0b + (size_t)m0 * 512);
            float v = __hip_atomic_load(base + 16 * s + 15, __ATOMIC_RELAXED,
                                        __HIP_MEMORY_SCOPE_AGENT);
            unsigned long long m = __ballot(__float_as_uint(v) != POISON);
            if (tid == 0 && m == ~0ull) ready = 1;
        }
        __syncthreads();
        if (ready) break;
        __builtin_amdgcn_s_sleep(64);
        __syncthreads();
    }

    // --- GEMM (A via atomic loads + poison retry) ---
    int lrow = tid >> 1;
    int lk = (tid & 1) * 8;
    int tx = tid & 15, ty = tid >> 4;

    float acc[8][8] = {};

    for (int kt = 0; kt < 1024; kt += GBK) {
        {
            int m = m0 + lrow;
            const float* base = (kt < 512) ? (h0f + (size_t)m * 512 + kt)
                                           : (h0b + (size_t)m * 512 + (kt - 512));
            const float* p = base + lk;
            unsigned long long q0, q1, q2, q3;
            for (;;) {
                q0 = ald64(p + 0);
                q1 = ald64(p + 2);
                q2 = ald64(p + 4);
                q3 = ald64(p + 6);
                if (!(pois2(q0) | pois2(q1) | pois2(q2) | pois2(q3))) break;
            }
            As[(lk + 0) * GLD + lrow] = __uint_as_float((unsigned)q0);
            As[(lk + 1) * GLD + lrow] = __uint_as_float((unsigned)(q0 >> 32));
            As[(lk + 2) * GLD + lrow] = __uint_as_float((unsigned)q1);
            As[(lk + 3) * GLD + lrow] = __uint_as_float((unsigned)(q1 >> 32));
            As[(lk + 4) * GLD + lrow] = __uint_as_float((unsigned)q2);
            As[(lk + 5) * GLD + lrow] = __uint_as_float((unsigned)(q2 >> 32));
            As[(lk + 6) * GLD + lrow] = __uint_as_float((unsigned)q3);
            As[(lk + 7) * GLD + lrow] = __uint_as_float((unsigned)(q3 >> 32));
        }
        {
            int n = n0 + lrow;
            const float* base = Bd + (size_t)n * 1024 + kt;
            float4 v0 = *(const float4*)(base + lk);
            float4 v1 = *(const float4*)(base + lk + 4);
            Bs[(lk + 0) * GLD + lrow] = v0.x;
            Bs[(lk + 1) * GLD + lrow] = v0.y;
            Bs[(lk + 2) * GLD + lrow] = v0.z;
            Bs[(lk + 3) * GLD + lrow] = v0.w;
            Bs[(lk + 4) * GLD + lrow] = v1.x;
            Bs[(lk + 5) * GLD + lrow] = v1.y;
            Bs[(lk + 6) * GLD + lrow] = v1.z;
            Bs[(lk + 7) * GLD + lrow] = v1.w;
        }
        __syncthreads();
#pragma unroll
        for (int kk = 0; kk < GBK; ++kk) {
            float4 a0 = *(const float4*)&As[kk * GLD + ty * 8];
            float4 a1 = *(const float4*)&As[kk * GLD + ty * 8 + 4];
            float4 b0 = *(const float4*)&Bs[kk * GLD + tx * 8];
            float4 b1 = *(const float4*)&Bs[kk * GLD + tx * 8 + 4];
            float av[8] = {a0.x, a0.y, a0.z, a0.w, a1.x, a1.y, a1.z, a1.w};
            float bv[8] = {b0.x, b0.y, b0.z, b0.w, b1.x, b1.y, b1.z, b1.w};
#pragma unroll
            for (int i = 0; i < 8; ++i)
#pragma unroll
                for (int j = 0; j < 8; ++j) acc[i][j] += av[i] * bv[j];
        }
        __syncthreads();
    }
#pragma unroll
    for (int i = 0; i < 8; ++i) {
        int m = m0 + ty * 8 + i;
#pragma unroll
        for (int j = 0; j < 8; ++j) {
            int n = n0 + tx * 8 + j;
            Cd[(size_t)m * 2048 + n] = acc[i][j] + bA[n] + bB[n];
        }
    }
}

// ---------------------------------------------------------------------------
// FUSED: lstm layer0 (WGs 0..63) + layer-1 input GEMM (WGs 64..575) in one
// dispatch. launch_bounds(256,3) caps VGPR at ~170 -> >=3 WGs/CU -> capacity
// >=768 co-resident slots > 576 launched WGs: every WG is resident regardless
// of dispatch order, so the polling GEMM WGs cannot starve the LSTM WGs.
// ---------------------------------------------------------------------------
__global__ __launch_bounds__(256, 3) void k_fused(
    const float* Whh0, float* Gi, float* h0,
    const float* Wih1, const float* bih1, const float* bhh1) {
    if (blockIdx.x < 64)
        lstm_body(blockIdx.x, Whh0, Gi, h0);
    else
        gemm1_body(blockIdx.x - 64, h0, Wih1, bih1, bhh1, Gi);
}

// ---------------------------------------------------------------------------
// K5: feats[t][tag] = concat(h1f[t],h1b[t]) . W_tag[tag] + b_tag[tag]
// ---------------------------------------------------------------------------
__global__ __launch_bounds__(64) void k_feats(
    const float* __restrict__ h1, const float* __restrict__ Wt,
    const float* __restrict__ bt, float* __restrict__ feats) {
    int t = blockIdx.x;
    int lane = threadIdx.x;
    __shared__ __align__(16) float xl[1024];
    const float4* hf = (const float4*)(h1 + (size_t)t * 512);
    const float4* hb = (const float4*)(h1 + (size_t)(2048 + t) * 512);
    ((float4*)xl)[lane] = hf[lane];
    ((float4*)xl)[lane + 64] = hf[lane + 64];
    ((float4*)xl)[128 + lane] = hb[lane];
    ((float4*)xl)[128 + lane + 64] = hb[lane + 64];
    __syncthreads();
    for (int tag = 0; tag < NTAGS; ++tag) {
        const float* wrow = Wt + tag * 1024;
        float s = 0.f;
        for (int k = lane; k < 1024; k += 64) s += xl[k] * wrow[k];
#pragma unroll
        for (int off = 32; off; off >>= 1) s += __shfl_xor(s, off);
        if (lane == 0) feats[t * NTAGS + tag] = s + bt[tag];
    }
}

// ---------------------------------------------------------------------------
// K6: Viterbi forward + backtrack, single 64-thread block.
// ---------------------------------------------------------------------------
__global__ __launch_bounds__(64) void k_viterbi(
    const float* __restrict__ feats, const float* __restrict__ trans,
    float* __restrict__ out) {
    __shared__ float fv[2][NTAGS];
    __shared__ unsigned char bp[SEQ * NTAGS];  // 24 KB
    __shared__ float featbuf[256 * NTAGS];     // 12 KB
    __shared__ float term[NTAGS];
    int lane = threadIdx.x;

    float tr[NTAGS];
    if (lane < NTAGS) {
#pragma unroll
        for (int p = 0; p < NTAGS; ++p) tr[p] = trans[lane * NTAGS + p];
        fv[0][lane] = (lane == START_TAG) ? 0.f : NEGV;
    }
    __syncthreads();

    int cur = 0;
    for (int tc = 0; tc < SEQ; tc += 256) {
        for (int i = lane; i < 256 * NTAGS; i += 64) featbuf[i] = feats[tc * NTAGS + i];
        __syncthreads();
        for (int tt = 0; tt < 256; ++tt) {
            int t = tc + tt;
            if (lane < NTAGS) {
                float best = fv[cur][0] + tr[0];
                int bi = 0;
#pragma unroll
                for (int p = 1; p < NTAGS; ++p) {
                    float s = fv[cur][p] + tr[p];
                    if (s > best) { best = s; bi = p; }  // strict > keeps first max
                }
                bp[t * NTAGS + lane] = (unsigned char)bi;
                fv[cur ^ 1][lane] = best + featbuf[tt * NTAGS + lane];
            }
            cur ^= 1;
            __syncthreads();
        }
    }

    if (lane < NTAGS) term[lane] = fv[cur][lane] + trans[STOP_TAG * NTAGS + lane];
    __syncthreads();
    if (lane == 0) {
        float best = term[0];
        int bi = 0;
        for (int p = 1; p < NTAGS; ++p) {
            if (term[p] > best) { best = term[p]; bi = p; }
        }
        out[0] = best;
        int tag = bi;
        out[1 + (SEQ - 1)] = (float)tag;
        for (int t = SEQ - 1; t >= 1; --t) {
            tag = bp[t * NTAGS + tag];
            out[t] = (float)tag;
        }
    }
}

// ---------------------------------------------------------------------------
extern "C" void kernel_launch(void* const* d_in, const int* in_sizes, int n_in,
                              void* d_out, int out_size, void* d_ws, size_t ws_size,
                              hipStream_t stream) {
    const int* sent = (const int*)d_in[0];
    const float* emb = (const float*)d_in[1];
    const float* Wih0 = (const float*)d_in[2];
    const float* Whh0 = (const float*)d_in[3];
    const float* bih0 = (const float*)d_in[4];
    const float* bhh0 = (const float*)d_in[5];
    const float* Wih1 = (const float*)d_in[6];
    const float* Whh1 = (const float*)d_in[7];
    const float* bih1 = (const float*)d_in[8];
    const float* bhh1 = (const float*)d_in[9];
    const float* Wtag = (const float*)d_in[10];
    const float* btag = (const float*)d_in[11];
    const float* trans = (const float*)d_in[12];
    float* out = (float*)d_out;

    char* ws = (char*)d_ws;
    size_t off = 0;
    auto alloc = [&](size_t bytes) {
        void* p = ws + off;
        off += (bytes + 255) & ~(size_t)255;
        return p;
    };
    float* x0 = (float*)alloc(2048ull * 512 * 4);          // 4 MB
    float* Gi = (float*)alloc(2ull * 2048 * 2048 * 4);     // 32 MB (layer0 then layer1)
    float* h0 = (float*)alloc(2ull * 2048 * 512 * 4);      // 8 MB
    float* h1 = (float*)alloc(2ull * 2048 * 512 * 4);      // 8 MB
    float* feats = (float*)alloc(2048ull * NTAGS * 4);

    // poison h buffers: "not yet written" sentinel for the data-polling sync
    hipMemsetAsync(h0, 0xAA, 2ull * 2048 * 512 * 4, stream);
    hipMemsetAsync(h1, 0xAA, 2ull * 2048 * 512 * 4, stream);

    k_embed<<<2048, 128, 0, stream>>>(sent, emb, x0);

    // layer 0 input gates: Gi = x0 @ Wih0^T + bih0 + bhh0  (K=512)
    k_gemm<<<dim3(16, 16, 2), 256, 0, stream>>>(x0, x0, Wih0, bih0, bhh0, Gi, 512);
    // FUSED: layer-0 recurrence + layer-1 input GEMM in its shadow
    k_fused<<<576, 256, 0, stream>>>(Whh0, Gi, h0, Wih1, bih1, bhh1);
    // layer 1 recurrence
    k_lstm<<<64, 256, 0, stream>>>(Whh1, Gi, h1);
    // tag projection
    k_feats<<<2048, 64, 0, stream>>>(h1, Wtag, btag, feats);
    // viterbi decode
    k_viterbi<<<1, 64, 0, stream>>>(feats, trans, out);
}